// Round 1
// baseline (37.404 us; speedup 1.0000x reference)
//
#include <hip/hip_runtime.h>
#include <hip/hip_bf16.h>

// out[i] = a[i, (int)z[i, attr]] * 0.999f
// z: [B,16] f32 (integer-valued), a: [B,10] f32, attr: scalar int (device 1-elem)

__global__ void __launch_bounds__(256)
cc_gather_kernel(const float* __restrict__ z,
                 const float* __restrict__ a,
                 const int* __restrict__ attr_p,
                 float* __restrict__ out,
                 int n)
{
    const int t  = blockIdx.x * blockDim.x + threadIdx.x;
    const long long i0 = (long long)t * 4;
    if (i0 >= n) return;

    const int attr = *attr_p;   // uniform scalar load

    if (i0 + 3 < n) {
        float4 r;
        float* rp = &r.x;
#pragma unroll
        for (int k = 0; k < 4; ++k) {
            const long long i = i0 + k;
            const int idx = (int)z[i * 16 + attr];
            rp[k] = a[i * 10 + idx] * 0.999f;
        }
        *reinterpret_cast<float4*>(out + i0) = r;
    } else {
        for (long long i = i0; i < n; ++i) {
            const int idx = (int)z[i * 16 + attr];
            out[i] = a[i * 10 + idx] * 0.999f;
        }
    }
}

extern "C" void kernel_launch(void* const* d_in, const int* in_sizes, int n_in,
                              void* d_out, int out_size, void* d_ws, size_t ws_size,
                              hipStream_t stream) {
    const float* z    = (const float*)d_in[0];
    const float* a    = (const float*)d_in[1];
    const int*   attr = (const int*)d_in[2];
    float* out = (float*)d_out;

    const int n = out_size;                 // B rows
    const int nthreads = (n + 3) / 4;       // 4 rows per thread
    const int block = 256;
    const int grid = (nthreads + block - 1) / block;

    cc_gather_kernel<<<grid, block, 0, stream>>>(z, a, attr, out, n);
}

// Round 3
// 36.315 us; speedup vs baseline: 1.0300x; 1.0300x over previous
//
#include <hip/hip_runtime.h>
#include <hip/hip_bf16.h>

// out[i] = a[i, (int)z[i, attr]] * 0.999f
// z: [B,16] f32 (integer-valued), a: [B,10] f32, attr: scalar int (device 1-elem)

#define ROWS_PER_THREAD 8

typedef float vfloat4 __attribute__((ext_vector_type(4)));

__global__ void __launch_bounds__(256)
cc_gather_kernel(const float* __restrict__ z,
                 const float* __restrict__ a,
                 const int* __restrict__ attr_p,
                 float* __restrict__ out,
                 int n)
{
    const int t  = blockIdx.x * blockDim.x + threadIdx.x;
    const long long i0 = (long long)t * ROWS_PER_THREAD;
    if (i0 >= n) return;

    const int attr = *attr_p;   // uniform scalar load
    const float* zc = z + attr; // column base; row stride 16 floats

    if (i0 + ROWS_PER_THREAD - 1 < n) {
        // Phase 1: issue all z column loads (independent -> in flight together)
        float zv[ROWS_PER_THREAD];
#pragma unroll
        for (int k = 0; k < ROWS_PER_THREAD; ++k)
            zv[k] = zc[(i0 + k) * 16];

        // Phase 2: issue all a gathers
        float av[ROWS_PER_THREAD];
#pragma unroll
        for (int k = 0; k < ROWS_PER_THREAD; ++k) {
            const int idx = (int)zv[k];
            av[k] = a[(i0 + k) * 10 + idx];
        }

        // Phase 3: scale + vector store (non-temporal: don't evict L3 inputs)
        vfloat4 r0, r1;
        r0.x = av[0] * 0.999f; r0.y = av[1] * 0.999f;
        r0.z = av[2] * 0.999f; r0.w = av[3] * 0.999f;
        r1.x = av[4] * 0.999f; r1.y = av[5] * 0.999f;
        r1.z = av[6] * 0.999f; r1.w = av[7] * 0.999f;
        __builtin_nontemporal_store(r0, reinterpret_cast<vfloat4*>(out + i0));
        __builtin_nontemporal_store(r1, reinterpret_cast<vfloat4*>(out + i0 + 4));
    } else {
        for (long long i = i0; i < n; ++i) {
            const int idx = (int)zc[i * 16];
            out[i] = a[i * 10 + idx] * 0.999f;
        }
    }
}

extern "C" void kernel_launch(void* const* d_in, const int* in_sizes, int n_in,
                              void* d_out, int out_size, void* d_ws, size_t ws_size,
                              hipStream_t stream) {
    const float* z    = (const float*)d_in[0];
    const float* a    = (const float*)d_in[1];
    const int*   attr = (const int*)d_in[2];
    float* out = (float*)d_out;

    const int n = out_size;                          // B rows
    const int nthreads = (n + ROWS_PER_THREAD - 1) / ROWS_PER_THREAD;
    const int block = 256;
    const int grid = (nthreads + block - 1) / block;

    cc_gather_kernel<<<grid, block, 0, stream>>>(z, a, attr, out, n);
}